// Round 1
// baseline (1187.341 us; speedup 1.0000x reference)
//
#include <hip/hip_runtime.h>
#include <cstdint>
#include <cstddef>

// ---------------------------------------------------------------------------
// FullyDynamicSTGNN: GAT(128 nodes, T=64, B=32) -> 2-layer Transformer(d=2048)
// -> linear head.  All heavy GEMMs in bf16 MFMA (16x16x32), everything else fp32.
// ---------------------------------------------------------------------------

typedef unsigned short u16;
typedef __bf16 bf16x8 __attribute__((ext_vector_type(8)));
typedef float f32x4 __attribute__((ext_vector_type(4)));
typedef unsigned int u32x4 __attribute__((ext_vector_type(4)));
typedef float f32x4v __attribute__((ext_vector_type(4)));

__device__ __forceinline__ u16 f2b(float f) {
  union { float f; unsigned u; } x; x.f = f;
  unsigned r = x.u + 0x7fffu + ((x.u >> 16) & 1u);   // RNE
  return (u16)(r >> 16);
}
__device__ __forceinline__ float b2f(u16 s) {
  union { unsigned u; float f; } x; x.u = ((unsigned)s) << 16;
  return x.f;
}

// async global->LDS, 16B per lane; lds dest must be wave-uniform base (+lane*16)
__device__ __forceinline__ void gload_lds16(const void* g, void* l) {
  __builtin_amdgcn_global_load_lds(
      (const __attribute__((address_space(1))) unsigned int*)g,
      (__attribute__((address_space(3))) unsigned int*)l, 16, 0, 0);
}

// ---------------------------------------------------------------------------
// GAT kernel: one block per (b,t) graph.  LDS ~146KB -> 1 block/CU.
// e[i][j] = att . leaky_relu(xl[i]+xr[j], 0.2) ; lrelu = 0.6x + 0.4|x|
// ---------------------------------------------------------------------------
__global__ __launch_bounds__(256) void gat_kernel(
    const float* __restrict__ X, const float* __restrict__ V_Adap,
    const int* __restrict__ class_idx,
    const float* __restrict__ Wl, const float* __restrict__ bl,
    const float* __restrict__ Wr, const float* __restrict__ br,
    const float* __restrict__ att, const float* __restrict__ gat_bias,
    const float* __restrict__ Wfc, const float* __restrict__ bfc,
    float* __restrict__ h_f32, u16* __restrict__ h_b16)
{
  const int bt = blockIdx.x;      // b*64 + t
  const int tid = threadIdx.x;

  __shared__ __align__(16) float Wls[16 * 64];
  __shared__ __align__(16) float Wrs[16 * 64];
  __shared__ __align__(16) float Wfcs[64 * 16];
  __shared__ __align__(16) float xls[128 * 65];   // pitch 65 (bank spread)
  __shared__ __align__(16) float xrs[128 * 65];   // reused for agg output
  __shared__ __align__(16) float es[128 * 128];
  __shared__ float cls[128], crs[128];
  __shared__ float atts[64], bls[64], brs[64], gbias[64], bfcs[16];

  for (int i = tid; i < 1024; i += 256) { Wls[i] = Wl[i]; Wrs[i] = Wr[i]; Wfcs[i] = Wfc[i]; }
  if (tid < 64) { atts[tid] = att[tid]; bls[tid] = bl[tid]; brs[tid] = br[tid]; gbias[tid] = gat_bias[tid]; }
  if (tid < 16) bfcs[tid] = bfc[tid];
  __syncthreads();

  // xl = x@Wl+bl, xr = x@Wr+br ; thread: node n = tid>>1, h-range 32
  {
    const int n = tid >> 1, h0 = (tid & 1) * 32;
    const float* xp = X + (size_t)bt * 2048 + n * 16;
    float xv[16];
    #pragma unroll
    for (int f4 = 0; f4 < 4; f4++) {
      f32x4v t4 = ((const f32x4v*)xp)[f4];
      xv[f4 * 4 + 0] = t4[0]; xv[f4 * 4 + 1] = t4[1];
      xv[f4 * 4 + 2] = t4[2]; xv[f4 * 4 + 3] = t4[3];
    }
    float accl[32], accr[32];
    #pragma unroll
    for (int hh = 0; hh < 32; hh++) { accl[hh] = bls[h0 + hh]; accr[hh] = brs[h0 + hh]; }
    for (int f = 0; f < 16; f++) {
      const float x1 = xv[f];
      #pragma unroll
      for (int hh = 0; hh < 32; hh++) {
        accl[hh] = fmaf(x1, Wls[f * 64 + h0 + hh], accl[hh]);
        accr[hh] = fmaf(x1, Wrs[f * 64 + h0 + hh], accr[hh]);
      }
    }
    #pragma unroll
    for (int hh = 0; hh < 32; hh++) {
      xls[n * 65 + h0 + hh] = accl[hh];
      xrs[n * 65 + h0 + hh] = accr[hh];
    }
  }
  __syncthreads();

  // cl[n] = att.xl[n], cr[n] = att.xr[n]
  if (tid < 128) {
    float s1 = 0.f, s2 = 0.f;
    for (int h = 0; h < 64; h++) {
      s1 = fmaf(atts[h], xls[tid * 65 + h], s1);
      s2 = fmaf(atts[h], xrs[tid * 65 + h], s2);
    }
    cls[tid] = s1; crs[tid] = s2;
  }
  __syncthreads();

  // e[i][j] with mask; thread tile 8i x 8j
  {
    const int i0 = (tid >> 4) * 8, j0 = (tid & 15) * 8;
    float acc[8][8] = {};
    for (int h = 0; h < 64; h++) {
      const float ah = atts[h];
      float xa[8], xb[8];
      #pragma unroll
      for (int a = 0; a < 8; a++) xa[a] = xls[(i0 + a) * 65 + h];
      #pragma unroll
      for (int b = 0; b < 8; b++) xb[b] = xrs[(j0 + b) * 65 + h];
      #pragma unroll
      for (int a = 0; a < 8; a++)
        #pragma unroll
        for (int b = 0; b < 8; b++)
          acc[a][b] = fmaf(ah, __builtin_fabsf(xa[a] + xb[b]), acc[a][b]);
    }
    const float* Vc = V_Adap + (size_t)(*class_idx) * 16384;
    #pragma unroll
    for (int a = 0; a < 8; a++) {
      const int i = i0 + a;
      #pragma unroll
      for (int b = 0; b < 8; b++) {
        const int j = j0 + b;
        const float e = 0.6f * (cls[i] + crs[j]) + 0.4f * acc[a][b];
        // sigmoid(v)/128 > 0.004  <=>  v > ln(0.512/0.488)
        const bool m = (Vc[i * 128 + j] > 0.04800922f) || (i == j);
        es[i * 128 + j] = m ? e : -1e9f;
      }
    }
  }
  __syncthreads();

  // softmax over sources i, per target column j
  if (tid < 128) {
    const int j = tid;
    float mx = -3e38f;
    for (int i = 0; i < 128; i++) mx = fmaxf(mx, es[i * 128 + j]);
    float s = 0.f;
    for (int i = 0; i < 128; i++) {
      const float p = __expf(es[i * 128 + j] - mx);
      es[i * 128 + j] = p; s += p;
    }
    const float inv = 1.f / s;
    for (int i = 0; i < 128; i++) es[i * 128 + j] *= inv;
  }
  __syncthreads();

  // agg[j][h] = sum_i alpha[i][j] * xl[i][h]  (thread tile 4j x 8h) -> xrs (reuse)
  {
    const int j0 = (tid >> 3) * 4, h0 = (tid & 7) * 8;
    float acc[4][8] = {};
    for (int i = 0; i < 128; i++) {
      float al[4], xv[8];
      #pragma unroll
      for (int a = 0; a < 4; a++) al[a] = es[i * 128 + j0 + a];
      #pragma unroll
      for (int c = 0; c < 8; c++) xv[c] = xls[i * 65 + h0 + c];
      #pragma unroll
      for (int a = 0; a < 4; a++)
        #pragma unroll
        for (int c = 0; c < 8; c++)
          acc[a][c] = fmaf(al[a], xv[c], acc[a][c]);
    }
    #pragma unroll
    for (int a = 0; a < 4; a++)
      #pragma unroll
      for (int c = 0; c < 8; c++)
        xrs[(j0 + a) * 65 + h0 + c] = acc[a][c];
  }
  __syncthreads();

  // final = (agg + gat_bias) @ Wfc + bfc  -> h (fp32 + bf16)
  {
    const int j = tid >> 1, s0 = (tid & 1) * 8;
    float o[8];
    #pragma unroll
    for (int ss = 0; ss < 8; ss++) o[ss] = bfcs[s0 + ss];
    for (int h = 0; h < 64; h++) {
      const float av = xrs[j * 65 + h] + gbias[h];
      #pragma unroll
      for (int ss = 0; ss < 8; ss++)
        o[ss] = fmaf(av, Wfcs[h * 16 + s0 + ss], o[ss]);
    }
    const size_t off = (size_t)bt * 2048 + j * 16 + s0;
    #pragma unroll
    for (int ss = 0; ss < 8; ss++) {
      h_f32[off + ss] = o[ss];
      h_b16[off + ss] = f2b(o[ss]);
    }
  }
}

// ---------------------------------------------------------------------------
// transpose + cast: src (2048 x 2048) fp32 row-major -> dst (2048 x 2048) bf16
// (dst[n][k] = src[k][n]).  Up to 3 matrices via blockIdx.z.
// ---------------------------------------------------------------------------
struct TransArgs {
  const float* s0; const float* s1; const float* s2;
  u16* d0; u16* d1; u16* d2;
};

__global__ __launch_bounds__(256) void transpose_cast(TransArgs p)
{
  const float* src = (blockIdx.z == 0) ? p.s0 : (blockIdx.z == 1) ? p.s1 : p.s2;
  u16* dst = (blockIdx.z == 0) ? p.d0 : (blockIdx.z == 1) ? p.d1 : p.d2;
  __shared__ u16 tile[64][66];
  const int k0 = blockIdx.y * 64, n0 = blockIdx.x * 64;
  const int tid = threadIdx.x;
  const int c = tid & 63, rb = tid >> 6;
  #pragma unroll
  for (int r = 0; r < 16; r++) {
    const int k = rb + r * 4;
    tile[k][c] = f2b(src[(size_t)(k0 + k) * 2048 + n0 + c]);
  }
  __syncthreads();
  #pragma unroll
  for (int r = 0; r < 16; r++) {
    const int n = rb + r * 4;
    dst[(size_t)(n0 + n) * 2048 + k0 + c] = tile[c][n];
  }
}

// ---------------------------------------------------------------------------
// bf16 MFMA GEMM (m97 structure): C[m][n] = sum_k A[m][k] * Bt[n][k] + bias[n]
// A (M x K) bf16 row-major, Bt (N x K) bf16 row-major.  128x128 tile, BK=32,
// 256 thr = 4 waves (2x2), each wave 4x4 of 16x16x32 MFMA.
// MODE 0: fp32 out ; 1: bf16 out ; 2: bf16 + relu
// ---------------------------------------------------------------------------
struct GemmArgs {
  const u16* A;
  const u16* Bt0; const u16* Bt1; const u16* Bt2;
  const float* b0; const float* b1; const float* b2;
  void* C0; void* C1; void* C2;
  int N; int K;
};

template <int MODE>
__global__ __launch_bounds__(256) void gemm_bt(GemmArgs g)
{
  const int z = blockIdx.z;
  const u16* Bt = (z == 0) ? g.Bt0 : (z == 1) ? g.Bt1 : g.Bt2;
  const float* bias = (z == 0) ? g.b0 : (z == 1) ? g.b1 : g.b2;
  void* C = (z == 0) ? g.C0 : (z == 1) ? g.C1 : g.C2;
  const int N = g.N, K = g.K;
  const int m0 = blockIdx.y * 128, n0 = blockIdx.x * 128;

  __shared__ __align__(16) u16 As[128 * 32];
  __shared__ __align__(16) u16 Bs[128 * 32];

  const int tid = threadIdx.x;
  const int lane = tid & 63, w = tid >> 6;
  const int srow = w * 16 + (lane >> 2);     // 0..63 in a 64-row group
  const int scol = (lane & 3) * 8;           // 8 bf16 = 16B per lane
  const u16* gA = g.A + (size_t)(m0 + srow) * K + scol;
  const u16* gB = Bt + (size_t)(n0 + srow) * K + scol;
  u16* lA0 = &As[(w * 16) * 32];
  u16* lA1 = &As[(64 + w * 16) * 32];
  u16* lB0 = &Bs[(w * 16) * 32];
  u16* lB1 = &Bs[(64 + w * 16) * 32];

  const int wm = (w >> 1) * 64, wn = (w & 1) * 64;
  const int lq = lane >> 4, lr = lane & 15;

  f32x4 acc[4][4] = {};

  for (int k0 = 0; k0 < K; k0 += 32) {
    gload_lds16(gA + k0, lA0);
    gload_lds16(gA + (size_t)64 * K + k0, lA1);
    gload_lds16(gB + k0, lB0);
    gload_lds16(gB + (size_t)64 * K + k0, lB1);
    __syncthreads();   // drains vmcnt(0): staging complete

    bf16x8 af[4], bf[4];
    #pragma unroll
    for (int i = 0; i < 4; i++) {
      af[i] = __builtin_bit_cast(bf16x8, *(const u32x4*)&As[(wm + i * 16 + lr) * 32 + lq * 8]);
      bf[i] = __builtin_bit_cast(bf16x8, *(const u32x4*)&Bs[(wn + i * 16 + lr) * 32 + lq * 8]);
    }
    #pragma unroll
    for (int mi = 0; mi < 4; mi++)
      #pragma unroll
      for (int ni = 0; ni < 4; ni++)
        acc[mi][ni] = __builtin_amdgcn_mfma_f32_16x16x32_bf16(af[mi], bf[ni], acc[mi][ni], 0, 0, 0);
    __syncthreads();   // LDS consumed, safe to restage
  }

  // epilogue: C/D layout col=lane&15, row=(lane>>4)*4+reg
  #pragma unroll
  for (int ni = 0; ni < 4; ni++) {
    const int col = n0 + wn + ni * 16 + lr;
    const float bv = bias[col];
    #pragma unroll
    for (int mi = 0; mi < 4; mi++) {
      #pragma unroll
      for (int r = 0; r < 4; r++) {
        const int row = m0 + wm + mi * 16 + lq * 4 + r;
        float v = acc[mi][ni][r] + bv;
        if (MODE == 0) {
          ((float*)C)[(size_t)row * N + col] = v;
        } else {
          if (MODE == 2) v = fmaxf(v, 0.f);
          ((u16*)C)[(size_t)row * N + col] = f2b(v);
        }
      }
    }
  }
}

// ---------------------------------------------------------------------------
// attention: one block per (head, batch).  S=64, DH=128, fp32 softmax in LDS.
// ---------------------------------------------------------------------------
__global__ __launch_bounds__(256) void attn_kernel(
    const u16* __restrict__ Qb, const u16* __restrict__ Kb,
    const u16* __restrict__ Vb, u16* __restrict__ AOb)
{
  const int head = blockIdx.x, b = blockIdx.y;
  const int tid = threadIdx.x;
  __shared__ __align__(16) float qs[64 * 129];
  __shared__ __align__(16) float ks[64 * 129];
  __shared__ __align__(16) float vs[64 * 128];
  __shared__ __align__(16) float ss[64 * 65];
  const size_t base = ((size_t)b * 64) * 2048 + (size_t)head * 128;

  for (int idx = tid; idx < 8192; idx += 256) {
    const int t_ = idx >> 7, d = idx & 127;
    const size_t gp = base + (size_t)t_ * 2048 + d;
    qs[t_ * 129 + d] = b2f(Qb[gp]);
    ks[t_ * 129 + d] = b2f(Kb[gp]);
    vs[t_ * 128 + d] = b2f(Vb[gp]);
  }
  __syncthreads();

  // scores: thread tile 4i x 4j
  {
    const int i0 = (tid >> 4) * 4, j0 = (tid & 15) * 4;
    float acc[4][4] = {};
    for (int d = 0; d < 128; d++) {
      float qv[4], kv[4];
      #pragma unroll
      for (int a = 0; a < 4; a++) qv[a] = qs[(i0 + a) * 129 + d];
      #pragma unroll
      for (int c = 0; c < 4; c++) kv[c] = ks[(j0 + c) * 129 + d];
      #pragma unroll
      for (int a = 0; a < 4; a++)
        #pragma unroll
        for (int c = 0; c < 4; c++)
          acc[a][c] = fmaf(qv[a], kv[c], acc[a][c]);
    }
    const float sc = 0.08838834764831845f;  // 1/sqrt(128)
    #pragma unroll
    for (int a = 0; a < 4; a++)
      #pragma unroll
      for (int c = 0; c < 4; c++)
        ss[(i0 + a) * 65 + j0 + c] = acc[a][c] * sc;
  }
  __syncthreads();

  if (tid < 64) {
    float mx = -3e38f;
    for (int j = 0; j < 64; j++) mx = fmaxf(mx, ss[tid * 65 + j]);
    float s = 0.f;
    for (int j = 0; j < 64; j++) {
      const float p = __expf(ss[tid * 65 + j] - mx);
      ss[tid * 65 + j] = p; s += p;
    }
    const float inv = 1.f / s;
    for (int j = 0; j < 64; j++) ss[tid * 65 + j] *= inv;
  }
  __syncthreads();

  // AV: thread tile 4i x 8d
  {
    const int i0 = (tid >> 4) * 4, d0 = (tid & 15) * 8;
    float o[4][8] = {};
    for (int j = 0; j < 64; j++) {
      float pv[4];
      #pragma unroll
      for (int a = 0; a < 4; a++) pv[a] = ss[(i0 + a) * 65 + j];
      f32x4v v0 = *(const f32x4v*)&vs[j * 128 + d0];
      f32x4v v1 = *(const f32x4v*)&vs[j * 128 + d0 + 4];
      float vv[8] = {v0[0], v0[1], v0[2], v0[3], v1[0], v1[1], v1[2], v1[3]};
      #pragma unroll
      for (int a = 0; a < 4; a++)
        #pragma unroll
        for (int c = 0; c < 8; c++)
          o[a][c] = fmaf(pv[a], vv[c], o[a][c]);
    }
    #pragma unroll
    for (int a = 0; a < 4; a++)
      #pragma unroll
      for (int c = 0; c < 8; c++)
        AOb[base + (size_t)(i0 + a) * 2048 + d0 + c] = f2b(o[a][c]);
  }
}

// ---------------------------------------------------------------------------
// fused residual + layernorm: h = LN(hin + delta) ; writes fp32 + bf16
// ---------------------------------------------------------------------------
__global__ __launch_bounds__(256) void ln_kernel(
    const float* __restrict__ hin, const float* __restrict__ delta,
    const float* __restrict__ gamma, const float* __restrict__ beta,
    float* __restrict__ hout, u16* __restrict__ bout_)
{
  const int token = blockIdx.x, tid = threadIdx.x;
  const size_t off = (size_t)token * 2048;
  __shared__ float red[8];
  float v[8];
  float s = 0.f;
  #pragma unroll
  for (int r = 0; r < 8; r++) {
    const int i = r * 256 + tid;
    v[r] = hin[off + i] + delta[off + i];
    s += v[r];
  }
  #pragma unroll
  for (int o = 32; o > 0; o >>= 1) s += __shfl_down(s, o, 64);
  if ((tid & 63) == 0) red[tid >> 6] = s;
  __syncthreads();
  const float mean = (red[0] + red[1] + red[2] + red[3]) * (1.f / 2048.f);
  float s2 = 0.f;
  #pragma unroll
  for (int r = 0; r < 8; r++) { const float d = v[r] - mean; s2 = fmaf(d, d, s2); }
  #pragma unroll
  for (int o = 32; o > 0; o >>= 1) s2 += __shfl_down(s2, o, 64);
  if ((tid & 63) == 0) red[4 + (tid >> 6)] = s2;
  __syncthreads();
  const float var = (red[4] + red[5] + red[6] + red[7]) * (1.f / 2048.f);
  const float rstd = rsqrtf(var + 1e-5f);
  #pragma unroll
  for (int r = 0; r < 8; r++) {
    const int i = r * 256 + tid;
    const float y = (v[r] - mean) * rstd * gamma[i] + beta[i];
    hout[off + i] = y;
    bout_[off + i] = f2b(y);
  }
}

// ---------------------------------------------------------------------------
// head: out[b][o] = h[b, T-1, :] . Wout[:, o] + bout[o]
// ---------------------------------------------------------------------------
__global__ __launch_bounds__(256) void final_kernel(
    const float* __restrict__ h, const float* __restrict__ Wout,
    const float* __restrict__ bout, float* __restrict__ out)
{
  const int b = blockIdx.x, tid = threadIdx.x;
  __shared__ float row[2048];
  __shared__ float part[256];
  const float* hr = h + ((size_t)b * 64 + 63) * 2048;
  for (int i = tid; i < 2048; i += 256) row[i] = hr[i];
  __syncthreads();
  const int o = tid & 15, ch = tid >> 4;
  float s = 0.f;
  if (o < 10) {
    const int i0 = ch * 128;
    for (int i = i0; i < i0 + 128; i++) s = fmaf(row[i], Wout[(size_t)i * 10 + o], s);
  }
  part[tid] = s;
  __syncthreads();
  if (tid < 10) {
    float t = bout[tid];
    for (int c2 = 0; c2 < 16; c2++) t += part[c2 * 16 + tid];
    out[(size_t)b * 10 + tid] = t;
  }
}

// ---------------------------------------------------------------------------
extern "C" void kernel_launch(void* const* d_in, const int* in_sizes, int n_in,
                              void* d_out, int out_size, void* d_ws, size_t ws_size,
                              hipStream_t stream)
{
  const float* X        = (const float*)d_in[0];
  const float* V_Adap   = (const float*)d_in[1];
  const float* Wl       = (const float*)d_in[2];
  const float* bl       = (const float*)d_in[3];
  const float* Wr       = (const float*)d_in[4];
  const float* br       = (const float*)d_in[5];
  const float* att      = (const float*)d_in[6];
  const float* gat_bias = (const float*)d_in[7];
  const float* Wfc      = (const float*)d_in[8];
  const float* bfc      = (const float*)d_in[9];
  const float* Wq       = (const float*)d_in[10];
  const float* bq       = (const float*)d_in[11];
  const float* Wk       = (const float*)d_in[12];
  const float* bk       = (const float*)d_in[13];
  const float* Wv       = (const float*)d_in[14];
  const float* bv       = (const float*)d_in[15];
  const float* Wo       = (const float*)d_in[16];
  const float* bo       = (const float*)d_in[17];
  const float* ln1_g    = (const float*)d_in[18];
  const float* ln1_b    = (const float*)d_in[19];
  const float* W1       = (const float*)d_in[20];
  const float* b1       = (const float*)d_in[21];
  const float* W2       = (const float*)d_in[22];
  const float* b2       = (const float*)d_in[23];
  const float* ln2_g    = (const float*)d_in[24];
  const float* ln2_b    = (const float*)d_in[25];
  const float* WoutP    = (const float*)d_in[26];
  const float* boutP    = (const float*)d_in[27];
  const int*   class_idx = (const int*)d_in[28];

  char* ws = (char*)d_ws;
  const size_t MB = (size_t)1 << 20;
  float* h_f32 = (float*)(ws);               // 16 MB  (B*T, D) fp32
  u16*   h_b16 = (u16*)(ws + 16 * MB);       //  8 MB
  u16*   Qb    = (u16*)(ws + 24 * MB);       //  8 MB
  u16*   Kb    = (u16*)(ws + 32 * MB);       //  8 MB
  u16*   Vb    = (u16*)(ws + 40 * MB);       //  8 MB
  u16*   AOb   = (u16*)(ws + 48 * MB);       //  8 MB
  float* tmp   = (float*)(ws + 56 * MB);     // 16 MB  (proj / ff2) fp32
  u16*   ff1b  = (u16*)(ws + 72 * MB);       //  8 MB
  u16*   Wt0   = (u16*)(ws + 80 * MB);       //  8 MB transposed bf16 weights
  u16*   Wt1   = (u16*)(ws + 88 * MB);       //  8 MB
  u16*   Wt2   = (u16*)(ws + 96 * MB);       //  8 MB   (total 104 MB)

  // 1. GAT over all (b,t) graphs -> h (fp32 + bf16)
  gat_kernel<<<2048, 256, 0, stream>>>(X, V_Adap, class_idx, Wl, bl, Wr, br,
                                       att, gat_bias, Wfc, bfc, h_f32, h_b16);

  const size_t DD = 2048ull * 2048ull;
  for (int l = 0; l < 2; l++) {
    const size_t wofs = (size_t)l * DD;
    const size_t bofs = (size_t)l * 2048;

    // QKV (batched z=3)
    transpose_cast<<<dim3(32, 32, 3), 256, 0, stream>>>(
        TransArgs{Wq + wofs, Wk + wofs, Wv + wofs, Wt0, Wt1, Wt2});
    gemm_bt<1><<<dim3(16, 16, 3), 256, 0, stream>>>(
        GemmArgs{h_b16, Wt0, Wt1, Wt2, bq + bofs, bk + bofs, bv + bofs,
                 Qb, Kb, Vb, 2048, 2048});

    attn_kernel<<<dim3(16, 32), 256, 0, stream>>>(Qb, Kb, Vb, AOb);

    // out-proj
    transpose_cast<<<dim3(32, 32, 1), 256, 0, stream>>>(
        TransArgs{Wo + wofs, nullptr, nullptr, Wt0, nullptr, nullptr});
    gemm_bt<0><<<dim3(16, 16, 1), 256, 0, stream>>>(
        GemmArgs{AOb, Wt0, nullptr, nullptr, bo + bofs, nullptr, nullptr,
                 tmp, nullptr, nullptr, 2048, 2048});
    ln_kernel<<<2048, 256, 0, stream>>>(h_f32, tmp, ln1_g + bofs, ln1_b + bofs,
                                        h_f32, h_b16);

    // FF1 (relu, bf16 out)
    transpose_cast<<<dim3(32, 32, 1), 256, 0, stream>>>(
        TransArgs{W1 + wofs, nullptr, nullptr, Wt0, nullptr, nullptr});
    gemm_bt<2><<<dim3(16, 16, 1), 256, 0, stream>>>(
        GemmArgs{h_b16, Wt0, nullptr, nullptr, b1 + bofs, nullptr, nullptr,
                 ff1b, nullptr, nullptr, 2048, 2048});

    // FF2
    transpose_cast<<<dim3(32, 32, 1), 256, 0, stream>>>(
        TransArgs{W2 + wofs, nullptr, nullptr, Wt0, nullptr, nullptr});
    gemm_bt<0><<<dim3(16, 16, 1), 256, 0, stream>>>(
        GemmArgs{ff1b, Wt0, nullptr, nullptr, b2 + bofs, nullptr, nullptr,
                 tmp, nullptr, nullptr, 2048, 2048});
    ln_kernel<<<2048, 256, 0, stream>>>(h_f32, tmp, ln2_g + bofs, ln2_b + bofs,
                                        h_f32, h_b16);
  }

  final_kernel<<<32, 256, 0, stream>>>(h_f32, WoutP, boutP, (float*)d_out);
}

// Round 2
// 1066.846 us; speedup vs baseline: 1.1129x; 1.1129x over previous
//
#include <hip/hip_runtime.h>
#include <cstdint>
#include <cstddef>

// ---------------------------------------------------------------------------
// FullyDynamicSTGNN: GAT(128 nodes, T=64, B=32) -> 2-layer Transformer(d=2048)
// -> linear head.  Heavy GEMMs in bf16 MFMA (16x16x32), everything else fp32.
// R2: GAT block 1024 (occupancy 11%->~50%), conflict-free LDS layouts, bf16
//     score matrix, fused softmax normalization; proj/ff1/ff2 GEMMs 128x64
//     tiles (512 blocks = 2/CU).
// ---------------------------------------------------------------------------

typedef unsigned short u16;
typedef __bf16 bf16x8 __attribute__((ext_vector_type(8)));
typedef float f32x4 __attribute__((ext_vector_type(4)));
typedef unsigned int u32x4 __attribute__((ext_vector_type(4)));
typedef float f32x4v __attribute__((ext_vector_type(4)));

__device__ __forceinline__ u16 f2b(float f) {
  union { float f; unsigned u; } x; x.f = f;
  unsigned r = x.u + 0x7fffu + ((x.u >> 16) & 1u);   // RNE
  return (u16)(r >> 16);
}
__device__ __forceinline__ float b2f(u16 s) {
  union { unsigned u; float f; } x; x.u = ((unsigned)s) << 16;
  return x.f;
}

// async global->LDS, 16B per lane; lds dest must be wave-uniform base (+lane*16)
__device__ __forceinline__ void gload_lds16(const void* g, void* l) {
  __builtin_amdgcn_global_load_lds(
      (const __attribute__((address_space(1))) unsigned int*)g,
      (__attribute__((address_space(3))) unsigned int*)l, 16, 0, 0);
}

// ---------------------------------------------------------------------------
// GAT kernel: one 1024-thread block per (b,t) graph.  16 waves/CU (occ 50%).
// e[i][j] = att . leaky_relu(xl[i]+xr[j], 0.2) ; lrelu = 0.6x + 0.4|x|
// LDS layouts (bank-conflict-checked, all <=2-way):
//   xlT[h][i] pitch 132 fp32 (e-stage A, b128 reads; reused as agg[j][h] p66)
//   xrT[h][j] pitch 132 fp32 (e-stage B)
//   xln[i][h] pitch 68  fp32 (aggregation, b128 reads)
//   esb[i][j] pitch 128 bf16 (scores -> unnormalized softmax p)
// ---------------------------------------------------------------------------
__global__ __launch_bounds__(1024) void gat_kernel(
    const float* __restrict__ X, const float* __restrict__ V_Adap,
    const int* __restrict__ class_idx,
    const float* __restrict__ Wl, const float* __restrict__ bl,
    const float* __restrict__ Wr, const float* __restrict__ br,
    const float* __restrict__ att, const float* __restrict__ gat_bias,
    const float* __restrict__ Wfc, const float* __restrict__ bfc,
    float* __restrict__ h_f32, u16* __restrict__ h_b16)
{
  const int bt = blockIdx.x;
  const int tid = threadIdx.x;

  __shared__ __align__(16) float xlT[64 * 132];     // 33792 B (also agg, p66)
  __shared__ __align__(16) float xrT[64 * 132];     // 33792 B
  __shared__ __align__(16) float xln[128 * 68];     // 34816 B
  __shared__ __align__(16) u16   esb[128 * 128];    // 32768 B
  __shared__ __align__(16) float WlT[64 * 20];      // 5120 B  [h][f] p20
  __shared__ __align__(16) float WrT[64 * 20];      // 5120 B
  __shared__ __align__(16) float Wfcs[64 * 16];     // 4096 B  [h][s]
  __shared__ float atts[64], bls[64], brs[64], gbias[64], bfcs[16];
  __shared__ float cls[128], crs[128], inv_s[128];
  __shared__ float red[8 * 128];                    // 4096 B

  // --- stage 0: load weights ---
  if (tid < 1024) {
    const int h = tid >> 4, f = tid & 15;
    WlT[h * 20 + f] = Wl[f * 64 + h];
    WrT[h * 20 + f] = Wr[f * 64 + h];
    Wfcs[tid] = Wfc[tid];
  }
  if (tid < 64) { atts[tid] = att[tid]; bls[tid] = bl[tid]; brs[tid] = br[tid]; gbias[tid] = gat_bias[tid]; }
  if (tid < 16) bfcs[tid] = bfc[tid];
  const int cidx = *class_idx;
  __syncthreads();

  // --- stage 1: xl = x@Wl+bl, xr = x@Wr+br ---
  // thread: node n = tid>>3, h = hq + 8k (k=0..7), hq = tid&7 (strided h!)
  {
    const int n = tid >> 3, hq = tid & 7;
    const float* xp = X + (size_t)bt * 2048 + n * 16;
    float xv[16];
    #pragma unroll
    for (int f4 = 0; f4 < 4; f4++) {
      f32x4v t4 = ((const f32x4v*)xp)[f4];
      xv[f4 * 4 + 0] = t4[0]; xv[f4 * 4 + 1] = t4[1];
      xv[f4 * 4 + 2] = t4[2]; xv[f4 * 4 + 3] = t4[3];
    }
    #pragma unroll
    for (int k = 0; k < 8; k++) {
      const int h = hq + 8 * k;
      float al = bls[h], ar = brs[h];
      #pragma unroll
      for (int f4 = 0; f4 < 4; f4++) {
        f32x4v wl = *(const f32x4v*)&WlT[h * 20 + f4 * 4];
        f32x4v wr = *(const f32x4v*)&WrT[h * 20 + f4 * 4];
        #pragma unroll
        for (int f = 0; f < 4; f++) {
          al = fmaf(xv[f4 * 4 + f], wl[f], al);
          ar = fmaf(xv[f4 * 4 + f], wr[f], ar);
        }
      }
      xlT[h * 132 + n] = al;
      xrT[h * 132 + n] = ar;
      xln[n * 68 + h] = al;
    }
  }
  __syncthreads();

  // --- stage 2: cl[n] = att.xl[n], cr[n] = att.xr[n] ---
  if (tid < 256) {
    const int n = tid & 127;
    const float* srcT = (tid < 128) ? xlT : xrT;
    float s = 0.f;
    for (int h = 0; h < 64; h++) s = fmaf(atts[h], srcT[h * 132 + n], s);
    if (tid < 128) cls[n] = s; else crs[n] = s;
  }
  __syncthreads();

  // --- stage 3: e[i][j] (thread tile 4i x 4j, j strided 32) ---
  {
    const int i0 = (tid >> 5) * 4;
    const int j0 = tid & 31;
    float acc[4][4] = {};
    #pragma unroll 2
    for (int h = 0; h < 64; h++) {
      const float ah = atts[h];
      f32x4v xa = *(const f32x4v*)&xlT[h * 132 + i0];
      float xb[4];
      #pragma unroll
      for (int b = 0; b < 4; b++) xb[b] = xrT[h * 132 + j0 + 32 * b];
      #pragma unroll
      for (int a = 0; a < 4; a++)
        #pragma unroll
        for (int b = 0; b < 4; b++)
          acc[a][b] = fmaf(ah, __builtin_fabsf(xa[a] + xb[b]), acc[a][b]);
    }
    const float* Vc = V_Adap + (size_t)cidx * 16384;
    #pragma unroll
    for (int a = 0; a < 4; a++) {
      const int i = i0 + a;
      const float ei = 0.6f * cls[i];
      #pragma unroll
      for (int b = 0; b < 4; b++) {
        const int j = j0 + 32 * b;
        const float e = ei + 0.6f * crs[j] + 0.4f * acc[a][b];
        // sigmoid(v)/128 > 0.004  <=>  v > ln(0.512/0.488)
        const bool m = (Vc[i * 128 + j] > 0.04800922f) || (i == j);
        esb[i * 128 + j] = f2b(m ? e : -1e9f);
      }
    }
  }
  __syncthreads();

  // --- stage 4: softmax over i per column j (no max pass: e is O(1),
  //     masked -1e9 -> exp=0; normalization deferred to aggregation) ---
  {
    const int j = tid & 127, c = tid >> 7;   // 8 chunks of 16 i
    float ps = 0.f;
    for (int i = c * 16; i < c * 16 + 16; i++) {
      const float p = __expf(b2f(esb[i * 128 + j]));
      esb[i * 128 + j] = f2b(p);
      ps += p;
    }
    red[c * 128 + j] = ps;
  }
  __syncthreads();
  if (tid < 128) {
    float s = 0.f;
    #pragma unroll
    for (int c = 0; c < 8; c++) s += red[c * 128 + tid];
    inv_s[tid] = 1.f / s;
  }
  __syncthreads();

  // --- stage 5: agg[j][h] = (1/s_j) sum_i p[i][j] * xl[i][h] -> xlT (p66) ---
  {
    const int j = tid >> 3, h0 = (tid & 7) * 8;
    float acc[8] = {};
    for (int i = 0; i < 128; i++) {
      const float p = b2f(esb[i * 128 + j]);
      f32x4v x0 = *(const f32x4v*)&xln[i * 68 + h0];
      f32x4v x1 = *(const f32x4v*)&xln[i * 68 + h0 + 4];
      #pragma unroll
      for (int c = 0; c < 4; c++) {
        acc[c] = fmaf(p, x0[c], acc[c]);
        acc[c + 4] = fmaf(p, x1[c], acc[c + 4]);
      }
    }
    const float sc = inv_s[j];
    float* aggb = xlT;   // xlT dead after stage 3
    #pragma unroll
    for (int c = 0; c < 8; c++) aggb[j * 66 + h0 + c] = acc[c] * sc;
  }
  __syncthreads();

  // --- stage 6: out = (agg + gat_bias) @ Wfc + bfc ---
  {
    const int j = tid >> 3, s0 = (tid & 7) * 2;
    const float* aggb = xlT;
    float o0 = bfcs[s0], o1 = bfcs[s0 + 1];
    for (int h = 0; h < 64; h++) {
      const float av = aggb[j * 66 + h] + gbias[h];
      o0 = fmaf(av, Wfcs[h * 16 + s0], o0);
      o1 = fmaf(av, Wfcs[h * 16 + s0 + 1], o1);
    }
    const size_t off = (size_t)bt * 2048 + j * 16 + s0;
    h_f32[off] = o0; h_f32[off + 1] = o1;
    h_b16[off] = f2b(o0); h_b16[off + 1] = f2b(o1);
  }
}

// ---------------------------------------------------------------------------
// transpose + cast: src (2048 x 2048) fp32 row-major -> dst bf16 (dst[n][k] =
// src[k][n]).  Up to 3 matrices via blockIdx.z.
// ---------------------------------------------------------------------------
struct TransArgs {
  const float* s0; const float* s1; const float* s2;
  u16* d0; u16* d1; u16* d2;
};

__global__ __launch_bounds__(256) void transpose_cast(TransArgs p)
{
  const float* src = (blockIdx.z == 0) ? p.s0 : (blockIdx.z == 1) ? p.s1 : p.s2;
  u16* dst = (blockIdx.z == 0) ? p.d0 : (blockIdx.z == 1) ? p.d1 : p.d2;
  __shared__ u16 tile[64][66];
  const int k0 = blockIdx.y * 64, n0 = blockIdx.x * 64;
  const int tid = threadIdx.x;
  const int c = tid & 63, rb = tid >> 6;
  #pragma unroll
  for (int r = 0; r < 16; r++) {
    const int k = rb + r * 4;
    tile[k][c] = f2b(src[(size_t)(k0 + k) * 2048 + n0 + c]);
  }
  __syncthreads();
  #pragma unroll
  for (int r = 0; r < 16; r++) {
    const int n = rb + r * 4;
    dst[(size_t)(n0 + n) * 2048 + k0 + c] = tile[c][n];
  }
}

// ---------------------------------------------------------------------------
// bf16 MFMA GEMM: C[m][n] = sum_k A[m][k] * Bt[n][k] + bias[n]
// 128x128 tile (for z-batched QKV) and 128x64 tile (single GEMMs, 512 blocks).
// MODE 0: fp32 out ; 1: bf16 out ; 2: bf16 + relu
// ---------------------------------------------------------------------------
struct GemmArgs {
  const u16* A;
  const u16* Bt0; const u16* Bt1; const u16* Bt2;
  const float* b0; const float* b1; const float* b2;
  void* C0; void* C1; void* C2;
  int N; int K;
};

template <int MODE>
__global__ __launch_bounds__(256) void gemm_bt(GemmArgs g)
{
  const int z = blockIdx.z;
  const u16* Bt = (z == 0) ? g.Bt0 : (z == 1) ? g.Bt1 : g.Bt2;
  const float* bias = (z == 0) ? g.b0 : (z == 1) ? g.b1 : g.b2;
  void* C = (z == 0) ? g.C0 : (z == 1) ? g.C1 : g.C2;
  const int N = g.N, K = g.K;
  const int m0 = blockIdx.y * 128, n0 = blockIdx.x * 128;

  __shared__ __align__(16) u16 As[128 * 32];
  __shared__ __align__(16) u16 Bs[128 * 32];

  const int tid = threadIdx.x;
  const int lane = tid & 63, w = tid >> 6;
  const int srow = w * 16 + (lane >> 2);
  const int scol = (lane & 3) * 8;
  const u16* gA = g.A + (size_t)(m0 + srow) * K + scol;
  const u16* gB = Bt + (size_t)(n0 + srow) * K + scol;
  u16* lA0 = &As[(w * 16) * 32];
  u16* lA1 = &As[(64 + w * 16) * 32];
  u16* lB0 = &Bs[(w * 16) * 32];
  u16* lB1 = &Bs[(64 + w * 16) * 32];

  const int wm = (w >> 1) * 64, wn = (w & 1) * 64;
  const int lq = lane >> 4, lr = lane & 15;

  f32x4 acc[4][4] = {};

  for (int k0 = 0; k0 < K; k0 += 32) {
    gload_lds16(gA + k0, lA0);
    gload_lds16(gA + (size_t)64 * K + k0, lA1);
    gload_lds16(gB + k0, lB0);
    gload_lds16(gB + (size_t)64 * K + k0, lB1);
    __syncthreads();

    bf16x8 af[4], bf[4];
    #pragma unroll
    for (int i = 0; i < 4; i++) {
      af[i] = __builtin_bit_cast(bf16x8, *(const u32x4*)&As[(wm + i * 16 + lr) * 32 + lq * 8]);
      bf[i] = __builtin_bit_cast(bf16x8, *(const u32x4*)&Bs[(wn + i * 16 + lr) * 32 + lq * 8]);
    }
    #pragma unroll
    for (int mi = 0; mi < 4; mi++)
      #pragma unroll
      for (int ni = 0; ni < 4; ni++)
        acc[mi][ni] = __builtin_amdgcn_mfma_f32_16x16x32_bf16(af[mi], bf[ni], acc[mi][ni], 0, 0, 0);
    __syncthreads();
  }

  #pragma unroll
  for (int ni = 0; ni < 4; ni++) {
    const int col = n0 + wn + ni * 16 + lr;
    const float bv = bias[col];
    #pragma unroll
    for (int mi = 0; mi < 4; mi++) {
      #pragma unroll
      for (int r = 0; r < 4; r++) {
        const int row = m0 + wm + mi * 16 + lq * 4 + r;
        float v = acc[mi][ni][r] + bv;
        if (MODE == 0) {
          ((float*)C)[(size_t)row * N + col] = v;
        } else {
          if (MODE == 2) v = fmaxf(v, 0.f);
          ((u16*)C)[(size_t)row * N + col] = f2b(v);
        }
      }
    }
  }
}

// 128(M) x 64(N) tile: grid (N/64, M/128) = 512 blocks -> 2 blocks/CU.
template <int MODE>
__global__ __launch_bounds__(256) void gemm_bt64(GemmArgs g)
{
  const u16* Bt = g.Bt0;
  const float* bias = g.b0;
  void* C = g.C0;
  const int N = g.N, K = g.K;
  const int m0 = blockIdx.y * 128, n0 = blockIdx.x * 64;

  __shared__ __align__(16) u16 As[128 * 32];
  __shared__ __align__(16) u16 Bs[64 * 32];

  const int tid = threadIdx.x;
  const int lane = tid & 63, w = tid >> 6;
  const int srow = w * 16 + (lane >> 2);
  const int scol = (lane & 3) * 8;
  const u16* gA = g.A + (size_t)(m0 + srow) * K + scol;
  const u16* gB = Bt + (size_t)(n0 + srow) * K + scol;
  u16* lA0 = &As[(w * 16) * 32];
  u16* lA1 = &As[(64 + w * 16) * 32];
  u16* lB0 = &Bs[(w * 16) * 32];

  const int wm = w * 32;             // 4 waves stacked along M
  const int lq = lane >> 4, lr = lane & 15;

  f32x4 acc[2][4] = {};

  for (int k0 = 0; k0 < K; k0 += 32) {
    gload_lds16(gA + k0, lA0);
    gload_lds16(gA + (size_t)64 * K + k0, lA1);
    gload_lds16(gB + k0, lB0);
    __syncthreads();

    bf16x8 af[2], bf[4];
    #pragma unroll
    for (int i = 0; i < 2; i++)
      af[i] = __builtin_bit_cast(bf16x8, *(const u32x4*)&As[(wm + i * 16 + lr) * 32 + lq * 8]);
    #pragma unroll
    for (int i = 0; i < 4; i++)
      bf[i] = __builtin_bit_cast(bf16x8, *(const u32x4*)&Bs[(i * 16 + lr) * 32 + lq * 8]);
    #pragma unroll
    for (int mi = 0; mi < 2; mi++)
      #pragma unroll
      for (int ni = 0; ni < 4; ni++)
        acc[mi][ni] = __builtin_amdgcn_mfma_f32_16x16x32_bf16(af[mi], bf[ni], acc[mi][ni], 0, 0, 0);
    __syncthreads();
  }

  #pragma unroll
  for (int ni = 0; ni < 4; ni++) {
    const int col = n0 + ni * 16 + lr;
    const float bv = bias[col];
    #pragma unroll
    for (int mi = 0; mi < 2; mi++) {
      #pragma unroll
      for (int r = 0; r < 4; r++) {
        const int row = m0 + wm + mi * 16 + lq * 4 + r;
        float v = acc[mi][ni][r] + bv;
        if (MODE == 0) {
          ((float*)C)[(size_t)row * N + col] = v;
        } else {
          if (MODE == 2) v = fmaxf(v, 0.f);
          ((u16*)C)[(size_t)row * N + col] = f2b(v);
        }
      }
    }
  }
}

// ---------------------------------------------------------------------------
// attention: one block per (head, batch).  S=64, DH=128, fp32 softmax in LDS.
// ---------------------------------------------------------------------------
__global__ __launch_bounds__(256) void attn_kernel(
    const u16* __restrict__ Qb, const u16* __restrict__ Kb,
    const u16* __restrict__ Vb, u16* __restrict__ AOb)
{
  const int head = blockIdx.x, b = blockIdx.y;
  const int tid = threadIdx.x;
  __shared__ __align__(16) float qs[64 * 129];
  __shared__ __align__(16) float ks[64 * 129];
  __shared__ __align__(16) float vs[64 * 128];
  __shared__ __align__(16) float ss[64 * 65];
  const size_t base = ((size_t)b * 64) * 2048 + (size_t)head * 128;

  for (int idx = tid; idx < 8192; idx += 256) {
    const int t_ = idx >> 7, d = idx & 127;
    const size_t gp = base + (size_t)t_ * 2048 + d;
    qs[t_ * 129 + d] = b2f(Qb[gp]);
    ks[t_ * 129 + d] = b2f(Kb[gp]);
    vs[t_ * 128 + d] = b2f(Vb[gp]);
  }
  __syncthreads();

  {
    const int i0 = (tid >> 4) * 4, j0 = (tid & 15) * 4;
    float acc[4][4] = {};
    for (int d = 0; d < 128; d++) {
      float qv[4], kv[4];
      #pragma unroll
      for (int a = 0; a < 4; a++) qv[a] = qs[(i0 + a) * 129 + d];
      #pragma unroll
      for (int c = 0; c < 4; c++) kv[c] = ks[(j0 + c) * 129 + d];
      #pragma unroll
      for (int a = 0; a < 4; a++)
        #pragma unroll
        for (int c = 0; c < 4; c++)
          acc[a][c] = fmaf(qv[a], kv[c], acc[a][c]);
    }
    const float sc = 0.08838834764831845f;  // 1/sqrt(128)
    #pragma unroll
    for (int a = 0; a < 4; a++)
      #pragma unroll
      for (int c = 0; c < 4; c++)
        ss[(i0 + a) * 65 + j0 + c] = acc[a][c] * sc;
  }
  __syncthreads();

  if (tid < 64) {
    float mx = -3e38f;
    for (int j = 0; j < 64; j++) mx = fmaxf(mx, ss[tid * 65 + j]);
    float s = 0.f;
    for (int j = 0; j < 64; j++) {
      const float p = __expf(ss[tid * 65 + j] - mx);
      ss[tid * 65 + j] = p; s += p;
    }
    const float inv = 1.f / s;
    for (int j = 0; j < 64; j++) ss[tid * 65 + j] *= inv;
  }
  __syncthreads();

  {
    const int i0 = (tid >> 4) * 4, d0 = (tid & 15) * 8;
    float o[4][8] = {};
    for (int j = 0; j < 64; j++) {
      float pv[4];
      #pragma unroll
      for (int a = 0; a < 4; a++) pv[a] = ss[(i0 + a) * 65 + j];
      f32x4v v0 = *(const f32x4v*)&vs[j * 128 + d0];
      f32x4v v1 = *(const f32x4v*)&vs[j * 128 + d0 + 4];
      float vv[8] = {v0[0], v0[1], v0[2], v0[3], v1[0], v1[1], v1[2], v1[3]};
      #pragma unroll
      for (int a = 0; a < 4; a++)
        #pragma unroll
        for (int c = 0; c < 8; c++)
          o[a][c] = fmaf(pv[a], vv[c], o[a][c]);
    }
    #pragma unroll
    for (int a = 0; a < 4; a++)
      #pragma unroll
      for (int c = 0; c < 8; c++)
        AOb[base + (size_t)(i0 + a) * 2048 + d0 + c] = f2b(o[a][c]);
  }
}

// ---------------------------------------------------------------------------
// fused residual + layernorm: h = LN(hin + delta) ; writes fp32 + bf16
// ---------------------------------------------------------------------------
__global__ __launch_bounds__(256) void ln_kernel(
    const float* __restrict__ hin, const float* __restrict__ delta,
    const float* __restrict__ gamma, const float* __restrict__ beta,
    float* __restrict__ hout, u16* __restrict__ bout_)
{
  const int token = blockIdx.x, tid = threadIdx.x;
  const size_t off = (size_t)token * 2048;
  __shared__ float red[8];
  float v[8];
  float s = 0.f;
  #pragma unroll
  for (int r = 0; r < 8; r++) {
    const int i = r * 256 + tid;
    v[r] = hin[off + i] + delta[off + i];
    s += v[r];
  }
  #pragma unroll
  for (int o = 32; o > 0; o >>= 1) s += __shfl_down(s, o, 64);
  if ((tid & 63) == 0) red[tid >> 6] = s;
  __syncthreads();
  const float mean = (red[0] + red[1] + red[2] + red[3]) * (1.f / 2048.f);
  float s2 = 0.f;
  #pragma unroll
  for (int r = 0; r < 8; r++) { const float d = v[r] - mean; s2 = fmaf(d, d, s2); }
  #pragma unroll
  for (int o = 32; o > 0; o >>= 1) s2 += __shfl_down(s2, o, 64);
  if ((tid & 63) == 0) red[4 + (tid >> 6)] = s2;
  __syncthreads();
  const float var = (red[4] + red[5] + red[6] + red[7]) * (1.f / 2048.f);
  const float rstd = rsqrtf(var + 1e-5f);
  #pragma unroll
  for (int r = 0; r < 8; r++) {
    const int i = r * 256 + tid;
    const float y = (v[r] - mean) * rstd * gamma[i] + beta[i];
    hout[off + i] = y;
    bout_[off + i] = f2b(y);
  }
}

// ---------------------------------------------------------------------------
// head: out[b][o] = h[b, T-1, :] . Wout[:, o] + bout[o]
// ---------------------------------------------------------------------------
__global__ __launch_bounds__(256) void final_kernel(
    const float* __restrict__ h, const float* __restrict__ Wout,
    const float* __restrict__ bout, float* __restrict__ out)
{
  const int b = blockIdx.x, tid = threadIdx.x;
  __shared__ float row[2048];
  __shared__ float part[256];
  const float* hr = h + ((size_t)b * 64 + 63) * 2048;
  for (int i = tid; i < 2048; i += 256) row[i] = hr[i];
  __syncthreads();
  const int o = tid & 15, ch = tid >> 4;
  float s = 0.f;
  if (o < 10) {
    const int i0 = ch * 128;
    for (int i = i0; i < i0 + 128; i++) s = fmaf(row[i], Wout[(size_t)i * 10 + o], s);
  }
  part[tid] = s;
  __syncthreads();
  if (tid < 10) {
    float t = bout[tid];
    for (int c2 = 0; c2 < 16; c2++) t += part[c2 * 16 + tid];
    out[(size_t)b * 10 + tid] = t;
  }
}

// ---------------------------------------------------------------------------
extern "C" void kernel_launch(void* const* d_in, const int* in_sizes, int n_in,
                              void* d_out, int out_size, void* d_ws, size_t ws_size,
                              hipStream_t stream)
{
  const float* X        = (const float*)d_in[0];
  const float* V_Adap   = (const float*)d_in[1];
  const float* Wl       = (const float*)d_in[2];
  const float* bl       = (const float*)d_in[3];
  const float* Wr       = (const float*)d_in[4];
  const float* br       = (const float*)d_in[5];
  const float* att      = (const float*)d_in[6];
  const float* gat_bias = (const float*)d_in[7];
  const float* Wfc      = (const float*)d_in[8];
  const float* bfc      = (const float*)d_in[9];
  const float* Wq       = (const float*)d_in[10];
  const float* bq       = (const float*)d_in[11];
  const float* Wk       = (const float*)d_in[12];
  const float* bk       = (const float*)d_in[13];
  const float* Wv       = (const float*)d_in[14];
  const float* bv       = (const float*)d_in[15];
  const float* Wo       = (const float*)d_in[16];
  const float* bo       = (const float*)d_in[17];
  const float* ln1_g    = (const float*)d_in[18];
  const float* ln1_b    = (const float*)d_in[19];
  const float* W1       = (const float*)d_in[20];
  const float* b1       = (const float*)d_in[21];
  const float* W2       = (const float*)d_in[22];
  const float* b2       = (const float*)d_in[23];
  const float* ln2_g    = (const float*)d_in[24];
  const float* ln2_b    = (const float*)d_in[25];
  const float* WoutP    = (const float*)d_in[26];
  const float* boutP    = (const float*)d_in[27];
  const int*   class_idx = (const int*)d_in[28];

  char* ws = (char*)d_ws;
  const size_t MB = (size_t)1 << 20;
  float* h_f32 = (float*)(ws);               // 16 MB  (B*T, D) fp32
  u16*   h_b16 = (u16*)(ws + 16 * MB);       //  8 MB
  u16*   Qb    = (u16*)(ws + 24 * MB);       //  8 MB
  u16*   Kb    = (u16*)(ws + 32 * MB);       //  8 MB
  u16*   Vb    = (u16*)(ws + 40 * MB);       //  8 MB
  u16*   AOb   = (u16*)(ws + 48 * MB);       //  8 MB
  float* tmp   = (float*)(ws + 56 * MB);     // 16 MB  (proj / ff2) fp32
  u16*   ff1b  = (u16*)(ws + 72 * MB);       //  8 MB
  u16*   Wt0   = (u16*)(ws + 80 * MB);       //  8 MB transposed bf16 weights
  u16*   Wt1   = (u16*)(ws + 88 * MB);       //  8 MB
  u16*   Wt2   = (u16*)(ws + 96 * MB);       //  8 MB   (total 104 MB)

  // 1. GAT over all (b,t) graphs -> h (fp32 + bf16)
  gat_kernel<<<2048, 1024, 0, stream>>>(X, V_Adap, class_idx, Wl, bl, Wr, br,
                                        att, gat_bias, Wfc, bfc, h_f32, h_b16);

  const size_t DD = 2048ull * 2048ull;
  for (int l = 0; l < 2; l++) {
    const size_t wofs = (size_t)l * DD;
    const size_t bofs = (size_t)l * 2048;

    // QKV (batched z=3, 768 blocks)
    transpose_cast<<<dim3(32, 32, 3), 256, 0, stream>>>(
        TransArgs{Wq + wofs, Wk + wofs, Wv + wofs, Wt0, Wt1, Wt2});
    gemm_bt<1><<<dim3(16, 16, 3), 256, 0, stream>>>(
        GemmArgs{h_b16, Wt0, Wt1, Wt2, bq + bofs, bk + bofs, bv + bofs,
                 Qb, Kb, Vb, 2048, 2048});

    attn_kernel<<<dim3(16, 32), 256, 0, stream>>>(Qb, Kb, Vb, AOb);

    // out-proj (128x64 tiles, 512 blocks)
    transpose_cast<<<dim3(32, 32, 1), 256, 0, stream>>>(
        TransArgs{Wo + wofs, nullptr, nullptr, Wt0, nullptr, nullptr});
    gemm_bt64<0><<<dim3(32, 16), 256, 0, stream>>>(
        GemmArgs{AOb, Wt0, nullptr, nullptr, bo + bofs, nullptr, nullptr,
                 tmp, nullptr, nullptr, 2048, 2048});
    ln_kernel<<<2048, 256, 0, stream>>>(h_f32, tmp, ln1_g + bofs, ln1_b + bofs,
                                        h_f32, h_b16);

    // FF1 (relu, bf16 out)
    transpose_cast<<<dim3(32, 32, 1), 256, 0, stream>>>(
        TransArgs{W1 + wofs, nullptr, nullptr, Wt0, nullptr, nullptr});
    gemm_bt64<2><<<dim3(32, 16), 256, 0, stream>>>(
        GemmArgs{h_b16, Wt0, nullptr, nullptr, b1 + bofs, nullptr, nullptr,
                 ff1b, nullptr, nullptr, 2048, 2048});

    // FF2
    transpose_cast<<<dim3(32, 32, 1), 256, 0, stream>>>(
        TransArgs{W2 + wofs, nullptr, nullptr, Wt0, nullptr, nullptr});
    gemm_bt64<0><<<dim3(32, 16), 256, 0, stream>>>(
        GemmArgs{ff1b, Wt0, nullptr, nullptr, b2 + bofs, nullptr, nullptr,
                 tmp, nullptr, nullptr, 2048, 2048});
    ln_kernel<<<2048, 256, 0, stream>>>(h_f32, tmp, ln2_g + bofs, ln2_b + bofs,
                                        h_f32, h_b16);
  }

  final_kernel<<<32, 256, 0, stream>>>(h_f32, WoutP, boutP, (float*)d_out);
}

// Round 3
// 966.523 us; speedup vs baseline: 1.2285x; 1.1038x over previous
//
#include <hip/hip_runtime.h>
#include <cstdint>
#include <cstddef>

// ---------------------------------------------------------------------------
// FullyDynamicSTGNN: GAT(128 nodes, T=64, B=32) -> 2-layer Transformer(d=2048)
// -> linear head.  Heavy GEMMs in bf16 MFMA (16x16x32), everything else fp32.
// R3: GAT stage-5 aggregation via MFMA (alpha^T stored transposed in bf16),
//     stage-3 all-b128 LDS reads, transpose launches consolidated (z=3).
// ---------------------------------------------------------------------------

typedef unsigned short u16;
typedef __bf16 bf16x8 __attribute__((ext_vector_type(8)));
typedef float f32x4 __attribute__((ext_vector_type(4)));
typedef unsigned int u32x4 __attribute__((ext_vector_type(4)));
typedef float f32x4v __attribute__((ext_vector_type(4)));
typedef unsigned short u16x4 __attribute__((ext_vector_type(4)));

__device__ __forceinline__ u16 f2b(float f) {
  union { float f; unsigned u; } x; x.f = f;
  unsigned r = x.u + 0x7fffu + ((x.u >> 16) & 1u);   // RNE
  return (u16)(r >> 16);
}
__device__ __forceinline__ float b2f(u16 s) {
  union { unsigned u; float f; } x; x.u = ((unsigned)s) << 16;
  return x.f;
}
__device__ __forceinline__ float b2f_lo(unsigned q) {
  union { unsigned u; float f; } x; x.u = q << 16;
  return x.f;
}
__device__ __forceinline__ float b2f_hi(unsigned q) {
  union { unsigned u; float f; } x; x.u = q & 0xffff0000u;
  return x.f;
}

// async global->LDS, 16B per lane; lds dest must be wave-uniform base (+lane*16)
__device__ __forceinline__ void gload_lds16(const void* g, void* l) {
  __builtin_amdgcn_global_load_lds(
      (const __attribute__((address_space(1))) unsigned int*)g,
      (__attribute__((address_space(3))) unsigned int*)l, 16, 0, 0);
}

// ---------------------------------------------------------------------------
// GAT kernel: one 1024-thread block per (b,t) graph.
// e[i][j] = att . leaky_relu(xl[i]+xr[j], 0.2) ; lrelu = 0.6x + 0.4|x|
// Stage 5 (agg[j][h] = sum_i alpha[i][j] xl[i][h]) via MFMA:
//   A = e^T[j][i] (bf16, k=i contiguous), B = xlTb[h][i] (bf16, k=i contig).
// LDS (159424 B total):
//   xlT/xrT fp32 [h][i] p132 (stages 2,3) ; xlTb bf16 [h][i] p136 (MFMA B)
//   esbT bf16 [j][i] p136 (stage3 out -> stage4 exp in-place -> MFMA A)
//   aggb bf16 [j][h] p72 (stage5 out -> stage6 in)
// ---------------------------------------------------------------------------
__global__ __launch_bounds__(1024) void gat_kernel(
    const float* __restrict__ X, const float* __restrict__ V_Adap,
    const int* __restrict__ class_idx,
    const float* __restrict__ Wl, const float* __restrict__ bl,
    const float* __restrict__ Wr, const float* __restrict__ br,
    const float* __restrict__ att, const float* __restrict__ gat_bias,
    const float* __restrict__ Wfc, const float* __restrict__ bfc,
    float* __restrict__ h_f32, u16* __restrict__ h_b16)
{
  const int bt = blockIdx.x;
  const int tid = threadIdx.x;

  __shared__ __align__(16) float xlT[64 * 132];     // 33792
  __shared__ __align__(16) float xrT[64 * 132];     // 33792
  __shared__ __align__(16) u16   xlTb[64 * 136];    // 17408
  __shared__ __align__(16) u16   esbT[128 * 136];   // 34816
  __shared__ __align__(16) u16   aggb[128 * 72];    // 18432
  __shared__ __align__(16) float WlT[64 * 20];      // 5120  [h][f]
  __shared__ __align__(16) float WrT[64 * 20];      // 5120
  __shared__ __align__(16) float WfcT[16 * 66];     // 4224  [s][h]
  __shared__ float atts[64], bls[64], brs[64], gbias[64], bfcs[16];
  __shared__ float cls[128], crs[128], inv_s[128];
  __shared__ float red[8 * 128];                    // 4096

  // --- stage 0: load weights ---
  {
    const int h = tid >> 4, f = tid & 15;
    WlT[h * 20 + f] = Wl[f * 64 + h];
    WrT[h * 20 + f] = Wr[f * 64 + h];
    WfcT[f * 66 + h] = Wfc[h * 16 + f];    // f plays 's' here
  }
  if (tid < 64) { atts[tid] = att[tid]; bls[tid] = bl[tid]; brs[tid] = br[tid]; gbias[tid] = gat_bias[tid]; }
  if (tid < 16) bfcs[tid] = bfc[tid];
  const int cidx = *class_idx;
  __syncthreads();

  // --- stage 1: xl = x@Wl+bl, xr = x@Wr+br (node n = tid>>3, h strided) ---
  {
    const int n = tid >> 3, hq = tid & 7;
    const float* xp = X + (size_t)bt * 2048 + n * 16;
    float xv[16];
    #pragma unroll
    for (int f4 = 0; f4 < 4; f4++) {
      f32x4v t4 = ((const f32x4v*)xp)[f4];
      xv[f4 * 4 + 0] = t4[0]; xv[f4 * 4 + 1] = t4[1];
      xv[f4 * 4 + 2] = t4[2]; xv[f4 * 4 + 3] = t4[3];
    }
    #pragma unroll
    for (int k = 0; k < 8; k++) {
      const int h = hq + 8 * k;
      float al = bls[h], ar = brs[h];
      #pragma unroll
      for (int f4 = 0; f4 < 4; f4++) {
        f32x4v wl = *(const f32x4v*)&WlT[h * 20 + f4 * 4];
        f32x4v wr = *(const f32x4v*)&WrT[h * 20 + f4 * 4];
        #pragma unroll
        for (int f = 0; f < 4; f++) {
          al = fmaf(xv[f4 * 4 + f], wl[f], al);
          ar = fmaf(xv[f4 * 4 + f], wr[f], ar);
        }
      }
      xlT[h * 132 + n] = al;
      xrT[h * 132 + n] = ar;
      xlTb[h * 136 + n] = f2b(al);
    }
  }
  __syncthreads();

  // --- stage 2: cl[n] = att.xl[n], cr[n] = att.xr[n] ---
  if (tid < 256) {
    const int n = tid & 127;
    const float* srcT = (tid < 128) ? xlT : xrT;
    float s = 0.f;
    for (int h = 0; h < 64; h++) s = fmaf(atts[h], srcT[h * 132 + n], s);
    if (tid < 128) cls[n] = s; else crs[n] = s;
  }
  __syncthreads();

  // --- stage 3: e[i][j], written TRANSPOSED to esbT[j][i] (bf16 x4 packed) ---
  {
    const int i0 = (tid >> 5) * 4;        // 0..124 step 4
    const int j0 = (tid & 31) * 4;        // 0..124 step 4
    float acc[4][4] = {};                 // [a=i][b=j]
    #pragma unroll 2
    for (int h = 0; h < 64; h++) {
      const float ah = atts[h];
      f32x4v xa = *(const f32x4v*)&xlT[h * 132 + i0];
      f32x4v xb = *(const f32x4v*)&xrT[h * 132 + j0];
      #pragma unroll
      for (int a = 0; a < 4; a++)
        #pragma unroll
        for (int b = 0; b < 4; b++)
          acc[a][b] = fmaf(ah, __builtin_fabsf(xa[a] + xb[b]), acc[a][b]);
    }
    const float* Vc = V_Adap + (size_t)cidx * 16384;
    float vm[4][4];
    #pragma unroll
    for (int a = 0; a < 4; a++) {
      f32x4v vc = *(const f32x4v*)&Vc[(size_t)(i0 + a) * 128 + j0];
      #pragma unroll
      for (int b = 0; b < 4; b++) vm[a][b] = vc[b];
    }
    #pragma unroll
    for (int b = 0; b < 4; b++) {
      const int j = j0 + b;
      const float ej = 0.6f * crs[j];
      u16x4 pk;
      #pragma unroll
      for (int a = 0; a < 4; a++) {
        const int i = i0 + a;
        const float e = ej + 0.6f * cls[i] + 0.4f * acc[a][b];
        // sigmoid(v)/128 > 0.004  <=>  v > ln(0.512/0.488)
        const bool m = (vm[a][b] > 0.04800922f) || (i == j);
        pk[a] = f2b(m ? e : -1e9f);
      }
      *(u16x4*)&esbT[j * 136 + i0] = pk;
    }
  }
  __syncthreads();

  // --- stage 4: p = exp(e) in-place on esbT rows; row-sum -> inv_s ---
  {
    const int j = tid >> 3, c = tid & 7;
    u16* rp = &esbT[j * 136 + c * 16];
    float ps = 0.f;
    #pragma unroll
    for (int half = 0; half < 2; half++) {
      u32x4 q = *(u32x4*)(rp + half * 8);
      #pragma unroll
      for (int w2 = 0; w2 < 4; w2++) {
        const float p0 = __expf(b2f_lo(q[w2]));
        const float p1 = __expf(b2f_hi(q[w2]));
        ps += p0 + p1;
        q[w2] = (unsigned)f2b(p0) | ((unsigned)f2b(p1) << 16);
      }
      *(u32x4*)(rp + half * 8) = q;
    }
    red[c * 128 + j] = ps;
  }
  __syncthreads();
  if (tid < 128) {
    float s = 0.f;
    #pragma unroll
    for (int c = 0; c < 8; c++) s += red[c * 128 + tid];
    inv_s[tid] = 1.f / s;
  }
  __syncthreads();

  // --- stage 5: agg[j][h] = (1/s_j) sum_i p^T[j][i] xl[i][h]  via MFMA ---
  // 8 j-tiles x 4 h-tiles = 32 MFMA tiles, 16 waves -> 2 tiles/wave, K=128.
  {
    const int w = tid >> 6, lane = tid & 63;
    const int lq = lane >> 4, lr = lane & 15;
    const int jt = w >> 1, ht0 = (w & 1) * 2;
    f32x4 acc2[2] = {};
    #pragma unroll
    for (int ks = 0; ks < 4; ks++) {
      const bf16x8 af = __builtin_bit_cast(bf16x8,
          *(const u32x4*)&esbT[(jt * 16 + lr) * 136 + ks * 32 + lq * 8]);
      #pragma unroll
      for (int t = 0; t < 2; t++) {
        const bf16x8 bfb = __builtin_bit_cast(bf16x8,
            *(const u32x4*)&xlTb[((ht0 + t) * 16 + lr) * 136 + ks * 32 + lq * 8]);
        acc2[t] = __builtin_amdgcn_mfma_f32_16x16x32_bf16(af, bfb, acc2[t], 0, 0, 0);
      }
    }
    // C layout: col(n=h-local)=lane&15, row(m=j-local)=lq*4+r.  agg += gbias.
    #pragma unroll
    for (int t = 0; t < 2; t++) {
      const int h = (ht0 + t) * 16 + lr;
      const float gb = gbias[h];
      #pragma unroll
      for (int r = 0; r < 4; r++) {
        const int j = jt * 16 + lq * 4 + r;
        aggb[j * 72 + h] = f2b(acc2[t][r] * inv_s[j] + gb);
      }
    }
  }
  __syncthreads();

  // --- stage 6: out = agg @ Wfc + bfc -> h (fp32 + bf16) ---
  {
    const int j = tid >> 3, s0 = (tid & 7) * 2;
    float o0 = bfcs[s0], o1 = bfcs[s0 + 1];
    #pragma unroll
    for (int h8 = 0; h8 < 8; h8++) {
      u32x4 q = *(const u32x4*)&aggb[j * 72 + h8 * 8];
      #pragma unroll
      for (int w2 = 0; w2 < 4; w2++) {
        const int h = h8 * 8 + w2 * 2;
        const float a0 = b2f_lo(q[w2]);
        const float a1 = b2f_hi(q[w2]);
        o0 = fmaf(a0, WfcT[s0 * 66 + h], o0);
        o1 = fmaf(a0, WfcT[(s0 + 1) * 66 + h], o1);
        o0 = fmaf(a1, WfcT[s0 * 66 + h + 1], o0);
        o1 = fmaf(a1, WfcT[(s0 + 1) * 66 + h + 1], o1);
      }
    }
    const size_t off = (size_t)bt * 2048 + j * 16 + s0;
    h_f32[off] = o0; h_f32[off + 1] = o1;
    h_b16[off] = f2b(o0); h_b16[off + 1] = f2b(o1);
  }
}

// ---------------------------------------------------------------------------
// transpose + cast: src (2048 x 2048) fp32 row-major -> dst bf16 (dst[n][k] =
// src[k][n]).  Up to 3 matrices via blockIdx.z.
// ---------------------------------------------------------------------------
struct TransArgs {
  const float* s0; const float* s1; const float* s2;
  u16* d0; u16* d1; u16* d2;
};

__global__ __launch_bounds__(256) void transpose_cast(TransArgs p)
{
  const float* src = (blockIdx.z == 0) ? p.s0 : (blockIdx.z == 1) ? p.s1 : p.s2;
  u16* dst = (blockIdx.z == 0) ? p.d0 : (blockIdx.z == 1) ? p.d1 : p.d2;
  __shared__ u16 tile[64][66];
  const int k0 = blockIdx.y * 64, n0 = blockIdx.x * 64;
  const int tid = threadIdx.x;
  const int c = tid & 63, rb = tid >> 6;
  #pragma unroll
  for (int r = 0; r < 16; r++) {
    const int k = rb + r * 4;
    tile[k][c] = f2b(src[(size_t)(k0 + k) * 2048 + n0 + c]);
  }
  __syncthreads();
  #pragma unroll
  for (int r = 0; r < 16; r++) {
    const int n = rb + r * 4;
    dst[(size_t)(n0 + n) * 2048 + k0 + c] = tile[c][n];
  }
}

// ---------------------------------------------------------------------------
// bf16 MFMA GEMM: C[m][n] = sum_k A[m][k] * Bt[n][k] + bias[n]
// 128x128 tile (z-batched QKV) and 128x64 tile (single GEMMs, 512 blocks).
// MODE 0: fp32 out ; 1: bf16 out ; 2: bf16 + relu
// ---------------------------------------------------------------------------
struct GemmArgs {
  const u16* A;
  const u16* Bt0; const u16* Bt1; const u16* Bt2;
  const float* b0; const float* b1; const float* b2;
  void* C0; void* C1; void* C2;
  int N; int K;
};

template <int MODE>
__global__ __launch_bounds__(256) void gemm_bt(GemmArgs g)
{
  const int z = blockIdx.z;
  const u16* Bt = (z == 0) ? g.Bt0 : (z == 1) ? g.Bt1 : g.Bt2;
  const float* bias = (z == 0) ? g.b0 : (z == 1) ? g.b1 : g.b2;
  void* C = (z == 0) ? g.C0 : (z == 1) ? g.C1 : g.C2;
  const int N = g.N, K = g.K;
  const int m0 = blockIdx.y * 128, n0 = blockIdx.x * 128;

  __shared__ __align__(16) u16 As[128 * 32];
  __shared__ __align__(16) u16 Bs[128 * 32];

  const int tid = threadIdx.x;
  const int lane = tid & 63, w = tid >> 6;
  const int srow = w * 16 + (lane >> 2);
  const int scol = (lane & 3) * 8;
  const u16* gA = g.A + (size_t)(m0 + srow) * K + scol;
  const u16* gB = Bt + (size_t)(n0 + srow) * K + scol;
  u16* lA0 = &As[(w * 16) * 32];
  u16* lA1 = &As[(64 + w * 16) * 32];
  u16* lB0 = &Bs[(w * 16) * 32];
  u16* lB1 = &Bs[(64 + w * 16) * 32];

  const int wm = (w >> 1) * 64, wn = (w & 1) * 64;
  const int lq = lane >> 4, lr = lane & 15;

  f32x4 acc[4][4] = {};

  for (int k0 = 0; k0 < K; k0 += 32) {
    gload_lds16(gA + k0, lA0);
    gload_lds16(gA + (size_t)64 * K + k0, lA1);
    gload_lds16(gB + k0, lB0);
    gload_lds16(gB + (size_t)64 * K + k0, lB1);
    __syncthreads();

    bf16x8 af[4], bf[4];
    #pragma unroll
    for (int i = 0; i < 4; i++) {
      af[i] = __builtin_bit_cast(bf16x8, *(const u32x4*)&As[(wm + i * 16 + lr) * 32 + lq * 8]);
      bf[i] = __builtin_bit_cast(bf16x8, *(const u32x4*)&Bs[(wn + i * 16 + lr) * 32 + lq * 8]);
    }
    #pragma unroll
    for (int mi = 0; mi < 4; mi++)
      #pragma unroll
      for (int ni = 0; ni < 4; ni++)
        acc[mi][ni] = __builtin_amdgcn_mfma_f32_16x16x32_bf16(af[mi], bf[ni], acc[mi][ni], 0, 0, 0);
    __syncthreads();
  }

  #pragma unroll
  for (int ni = 0; ni < 4; ni++) {
    const int col = n0 + wn + ni * 16 + lr;
    const float bv = bias[col];
    #pragma unroll
    for (int mi = 0; mi < 4; mi++) {
      #pragma unroll
      for (int r = 0; r < 4; r++) {
        const int row = m0 + wm + mi * 16 + lq * 4 + r;
        float v = acc[mi][ni][r] + bv;
        if (MODE == 0) {
          ((float*)C)[(size_t)row * N + col] = v;
        } else {
          if (MODE == 2) v = fmaxf(v, 0.f);
          ((u16*)C)[(size_t)row * N + col] = f2b(v);
        }
      }
    }
  }
}

// 128(M) x 64(N) tile: grid (N/64, M/128) = 512 blocks -> 2 blocks/CU.
template <int MODE>
__global__ __launch_bounds__(256) void gemm_bt64(GemmArgs g)
{
  const u16* Bt = g.Bt0;
  const float* bias = g.b0;
  void* C = g.C0;
  const int N = g.N, K = g.K;
  const int m0 = blockIdx.y * 128, n0 = blockIdx.x * 64;

  __shared__ __align__(16) u16 As[128 * 32];
  __shared__ __align__(16) u16 Bs[64 * 32];

  const int tid = threadIdx.x;
  const int lane = tid & 63, w = tid >> 6;
  const int srow = w * 16 + (lane >> 2);
  const int scol = (lane & 3) * 8;
  const u16* gA = g.A + (size_t)(m0 + srow) * K + scol;
  const u16* gB = Bt + (size_t)(n0 + srow) * K + scol;
  u16* lA0 = &As[(w * 16) * 32];
  u16* lA1 = &As[(64 + w * 16) * 32];
  u16* lB0 = &Bs[(w * 16) * 32];

  const int wm = w * 32;
  const int lq = lane >> 4, lr = lane & 15;

  f32x4 acc[2][4] = {};

  for (int k0 = 0; k0 < K; k0 += 32) {
    gload_lds16(gA + k0, lA0);
    gload_lds16(gA + (size_t)64 * K + k0, lA1);
    gload_lds16(gB + k0, lB0);
    __syncthreads();

    bf16x8 af[2], bf[4];
    #pragma unroll
    for (int i = 0; i < 2; i++)
      af[i] = __builtin_bit_cast(bf16x8, *(const u32x4*)&As[(wm + i * 16 + lr) * 32 + lq * 8]);
    #pragma unroll
    for (int i = 0; i < 4; i++)
      bf[i] = __builtin_bit_cast(bf16x8, *(const u32x4*)&Bs[(i * 16 + lr) * 32 + lq * 8]);
    #pragma unroll
    for (int mi = 0; mi < 2; mi++)
      #pragma unroll
      for (int ni = 0; ni < 4; ni++)
        acc[mi][ni] = __builtin_amdgcn_mfma_f32_16x16x32_bf16(af[mi], bf[ni], acc[mi][ni], 0, 0, 0);
    __syncthreads();
  }

  #pragma unroll
  for (int ni = 0; ni < 4; ni++) {
    const int col = n0 + ni * 16 + lr;
    const float bv = bias[col];
    #pragma unroll
    for (int mi = 0; mi < 2; mi++) {
      #pragma unroll
      for (int r = 0; r < 4; r++) {
        const int row = m0 + wm + mi * 16 + lq * 4 + r;
        float v = acc[mi][ni][r] + bv;
        if (MODE == 0) {
          ((float*)C)[(size_t)row * N + col] = v;
        } else {
          if (MODE == 2) v = fmaxf(v, 0.f);
          ((u16*)C)[(size_t)row * N + col] = f2b(v);
        }
      }
    }
  }
}

// ---------------------------------------------------------------------------
// attention: one block per (head, batch).  S=64, DH=128, fp32 softmax in LDS.
// ---------------------------------------------------------------------------
__global__ __launch_bounds__(256) void attn_kernel(
    const u16* __restrict__ Qb, const u16* __restrict__ Kb,
    const u16* __restrict__ Vb, u16* __restrict__ AOb)
{
  const int head = blockIdx.x, b = blockIdx.y;
  const int tid = threadIdx.x;
  __shared__ __align__(16) float qs[64 * 129];
  __shared__ __align__(16) float ks[64 * 129];
  __shared__ __align__(16) float vs[64 * 128];
  __shared__ __align__(16) float ss[64 * 65];
  const size_t base = ((size_t)b * 64) * 2048 + (size_t)head * 128;

  for (int idx = tid; idx < 8192; idx += 256) {
    const int t_ = idx >> 7, d = idx & 127;
    const size_t gp = base + (size_t)t_ * 2048 + d;
    qs[t_ * 129 + d] = b2f(Qb[gp]);
    ks[t_ * 129 + d] = b2f(Kb[gp]);
    vs[t_ * 128 + d] = b2f(Vb[gp]);
  }
  __syncthreads();

  {
    const int i0 = (tid >> 4) * 4, j0 = (tid & 15) * 4;
    float acc[4][4] = {};
    for (int d = 0; d < 128; d++) {
      float qv[4], kv[4];
      #pragma unroll
      for (int a = 0; a < 4; a++) qv[a] = qs[(i0 + a) * 129 + d];
      #pragma unroll
      for (int c = 0; c < 4; c++) kv[c] = ks[(j0 + c) * 129 + d];
      #pragma unroll
      for (int a = 0; a < 4; a++)
        #pragma unroll
        for (int c = 0; c < 4; c++)
          acc[a][c] = fmaf(qv[a], kv[c], acc[a][c]);
    }
    const float sc = 0.08838834764831845f;  // 1/sqrt(128)
    #pragma unroll
    for (int a = 0; a < 4; a++)
      #pragma unroll
      for (int c = 0; c < 4; c++)
        ss[(i0 + a) * 65 + j0 + c] = acc[a][c] * sc;
  }
  __syncthreads();

  if (tid < 64) {
    float mx = -3e38f;
    for (int j = 0; j < 64; j++) mx = fmaxf(mx, ss[tid * 65 + j]);
    float s = 0.f;
    for (int j = 0; j < 64; j++) {
      const float p = __expf(ss[tid * 65 + j] - mx);
      ss[tid * 65 + j] = p; s += p;
    }
    const float inv = 1.f / s;
    for (int j = 0; j < 64; j++) ss[tid * 65 + j] *= inv;
  }
  __syncthreads();

  {
    const int i0 = (tid >> 4) * 4, d0 = (tid & 15) * 8;
    float o[4][8] = {};
    for (int j = 0; j < 64; j++) {
      float pv[4];
      #pragma unroll
      for (int a = 0; a < 4; a++) pv[a] = ss[(i0 + a) * 65 + j];
      f32x4v v0 = *(const f32x4v*)&vs[j * 128 + d0];
      f32x4v v1 = *(const f32x4v*)&vs[j * 128 + d0 + 4];
      float vv[8] = {v0[0], v0[1], v0[2], v0[3], v1[0], v1[1], v1[2], v1[3]};
      #pragma unroll
      for (int a = 0; a < 4; a++)
        #pragma unroll
        for (int c = 0; c < 8; c++)
          o[a][c] = fmaf(pv[a], vv[c], o[a][c]);
    }
    #pragma unroll
    for (int a = 0; a < 4; a++)
      #pragma unroll
      for (int c = 0; c < 8; c++)
        AOb[base + (size_t)(i0 + a) * 2048 + d0 + c] = f2b(o[a][c]);
  }
}

// ---------------------------------------------------------------------------
// fused residual + layernorm: h = LN(hin + delta) ; writes fp32 + bf16
// ---------------------------------------------------------------------------
__global__ __launch_bounds__(256) void ln_kernel(
    const float* __restrict__ hin, const float* __restrict__ delta,
    const float* __restrict__ gamma, const float* __restrict__ beta,
    float* __restrict__ hout, u16* __restrict__ bout_)
{
  const int token = blockIdx.x, tid = threadIdx.x;
  const size_t off = (size_t)token * 2048;
  __shared__ float red[8];
  float v[8];
  float s = 0.f;
  #pragma unroll
  for (int r = 0; r < 8; r++) {
    const int i = r * 256 + tid;
    v[r] = hin[off + i] + delta[off + i];
    s += v[r];
  }
  #pragma unroll
  for (int o = 32; o > 0; o >>= 1) s += __shfl_down(s, o, 64);
  if ((tid & 63) == 0) red[tid >> 6] = s;
  __syncthreads();
  const float mean = (red[0] + red[1] + red[2] + red[3]) * (1.f / 2048.f);
  float s2 = 0.f;
  #pragma unroll
  for (int r = 0; r < 8; r++) { const float d = v[r] - mean; s2 = fmaf(d, d, s2); }
  #pragma unroll
  for (int o = 32; o > 0; o >>= 1) s2 += __shfl_down(s2, o, 64);
  if ((tid & 63) == 0) red[4 + (tid >> 6)] = s2;
  __syncthreads();
  const float var = (red[4] + red[5] + red[6] + red[7]) * (1.f / 2048.f);
  const float rstd = rsqrtf(var + 1e-5f);
  #pragma unroll
  for (int r = 0; r < 8; r++) {
    const int i = r * 256 + tid;
    const float y = (v[r] - mean) * rstd * gamma[i] + beta[i];
    hout[off + i] = y;
    bout_[off + i] = f2b(y);
  }
}

// ---------------------------------------------------------------------------
// head: out[b][o] = h[b, T-1, :] . Wout[:, o] + bout[o]
// ---------------------------------------------------------------------------
__global__ __launch_bounds__(256) void final_kernel(
    const float* __restrict__ h, const float* __restrict__ Wout,
    const float* __restrict__ bout, float* __restrict__ out)
{
  const int b = blockIdx.x, tid = threadIdx.x;
  __shared__ float row[2048];
  __shared__ float part[256];
  const float* hr = h + ((size_t)b * 64 + 63) * 2048;
  for (int i = tid; i < 2048; i += 256) row[i] = hr[i];
  __syncthreads();
  const int o = tid & 15, ch = tid >> 4;
  float s = 0.f;
  if (o < 10) {
    const int i0 = ch * 128;
    for (int i = i0; i < i0 + 128; i++) s = fmaf(row[i], Wout[(size_t)i * 10 + o], s);
  }
  part[tid] = s;
  __syncthreads();
  if (tid < 10) {
    float t = bout[tid];
    for (int c2 = 0; c2 < 16; c2++) t += part[c2 * 16 + tid];
    out[(size_t)b * 10 + tid] = t;
  }
}

// ---------------------------------------------------------------------------
extern "C" void kernel_launch(void* const* d_in, const int* in_sizes, int n_in,
                              void* d_out, int out_size, void* d_ws, size_t ws_size,
                              hipStream_t stream)
{
  const float* X        = (const float*)d_in[0];
  const float* V_Adap   = (const float*)d_in[1];
  const float* Wl       = (const float*)d_in[2];
  const float* bl       = (const float*)d_in[3];
  const float* Wr       = (const float*)d_in[4];
  const float* br       = (const float*)d_in[5];
  const float* att      = (const float*)d_in[6];
  const float* gat_bias = (const float*)d_in[7];
  const float* Wfc      = (const float*)d_in[8];
  const float* bfc      = (const float*)d_in[9];
  const float* Wq       = (const float*)d_in[10];
  const float* bq       = (const float*)d_in[11];
  const float* Wk       = (const float*)d_in[12];
  const float* bk       = (const float*)d_in[13];
  const float* Wv       = (const float*)d_in[14];
  const float* bv       = (const float*)d_in[15];
  const float* Wo       = (const float*)d_in[16];
  const float* bo       = (const float*)d_in[17];
  const float* ln1_g    = (const float*)d_in[18];
  const float* ln1_b    = (const float*)d_in[19];
  const float* W1       = (const float*)d_in[20];
  const float* b1       = (const float*)d_in[21];
  const float* W2       = (const float*)d_in[22];
  const float* b2       = (const float*)d_in[23];
  const float* ln2_g    = (const float*)d_in[24];
  const float* ln2_b    = (const float*)d_in[25];
  const float* WoutP    = (const float*)d_in[26];
  const float* boutP    = (const float*)d_in[27];
  const int*   class_idx = (const int*)d_in[28];

  char* ws = (char*)d_ws;
  const size_t MB = (size_t)1 << 20;
  float* h_f32 = (float*)(ws);               // 16 MB  (B*T, D) fp32
  u16*   h_b16 = (u16*)(ws + 16 * MB);       //  8 MB
  u16*   Qb    = (u16*)(ws + 24 * MB);       //  8 MB
  u16*   Kb    = (u16*)(ws + 32 * MB);       //  8 MB
  u16*   Vb    = (u16*)(ws + 40 * MB);       //  8 MB
  u16*   AOb   = (u16*)(ws + 48 * MB);       //  8 MB
  float* tmp   = (float*)(ws + 56 * MB);     // 16 MB  (proj / ff2) fp32
  u16*   ff1b  = (u16*)(ws + 72 * MB);       //  8 MB
  u16*   Wt0   = (u16*)(ws + 80 * MB);       //  8 MB transposed bf16 weights
  u16*   Wt1   = (u16*)(ws + 88 * MB);       //  8 MB
  u16*   Wt2   = (u16*)(ws + 96 * MB);       //  8 MB   (total 104 MB)

  // 1. GAT over all (b,t) graphs -> h (fp32 + bf16)
  gat_kernel<<<2048, 1024, 0, stream>>>(X, V_Adap, class_idx, Wl, bl, Wr, br,
                                        att, gat_bias, Wfc, bfc, h_f32, h_b16);

  const size_t DD = 2048ull * 2048ull;
  for (int l = 0; l < 2; l++) {
    const size_t wofs = (size_t)l * DD;
    const size_t bofs = (size_t)l * 2048;

    // QKV (batched z=3, 768 blocks)
    transpose_cast<<<dim3(32, 32, 3), 256, 0, stream>>>(
        TransArgs{Wq + wofs, Wk + wofs, Wv + wofs, Wt0, Wt1, Wt2});
    gemm_bt<1><<<dim3(16, 16, 3), 256, 0, stream>>>(
        GemmArgs{h_b16, Wt0, Wt1, Wt2, bq + bofs, bk + bofs, bv + bofs,
                 Qb, Kb, Vb, 2048, 2048});

    attn_kernel<<<dim3(16, 32), 256, 0, stream>>>(Qb, Kb, Vb, AOb);

    // o / W1 / W2 transposed together (Wt0..2 free once QKV gemm is done)
    transpose_cast<<<dim3(32, 32, 3), 256, 0, stream>>>(
        TransArgs{Wo + wofs, W1 + wofs, W2 + wofs, Wt0, Wt1, Wt2});

    // out-proj (128x64 tiles, 512 blocks)
    gemm_bt64<0><<<dim3(32, 16), 256, 0, stream>>>(
        GemmArgs{AOb, Wt0, nullptr, nullptr, bo + bofs, nullptr, nullptr,
                 tmp, nullptr, nullptr, 2048, 2048});
    ln_kernel<<<2048, 256, 0, stream>>>(h_f32, tmp, ln1_g + bofs, ln1_b + bofs,
                                        h_f32, h_b16);

    // FF1 (relu, bf16 out)
    gemm_bt64<2><<<dim3(32, 16), 256, 0, stream>>>(
        GemmArgs{h_b16, Wt1, nullptr, nullptr, b1 + bofs, nullptr, nullptr,
                 ff1b, nullptr, nullptr, 2048, 2048});

    // FF2
    gemm_bt64<0><<<dim3(32, 16), 256, 0, stream>>>(
        GemmArgs{ff1b, Wt2, nullptr, nullptr, b2 + bofs, nullptr, nullptr,
                 tmp, nullptr, nullptr, 2048, 2048});
    ln_kernel<<<2048, 256, 0, stream>>>(h_f32, tmp, ln2_g + bofs, ln2_b + bofs,
                                        h_f32, h_b16);
  }

  final_kernel<<<32, 256, 0, stream>>>(h_f32, WoutP, boutP, (float*)d_out);
}